// Round 7
// baseline (344.917 us; speedup 1.0000x reference)
//
#include <hip/hip_runtime.h>

#define T_TOK 32768   // B*S
#define NQ    8
#define FFN   2048
#define EMB   512
#define BM    128
#define BN    128
#define BK    32
#define NCHUNK (FFN / BK)   // 64

typedef __attribute__((ext_vector_type(8)))  short short8;
typedef __attribute__((ext_vector_type(16))) float f32x16;
typedef __attribute__((ext_vector_type(2)))  unsigned int u32x2;

__device__ __forceinline__ unsigned short f2bf(float f) {
  unsigned int u = __float_as_uint(f);
  u += 0x7fffu + ((u >> 16) & 1u);
  return (unsigned short)(u >> 16);
}

__device__ __forceinline__ unsigned pk2bf(float lo, float hi) {
#if __has_builtin(__builtin_amdgcn_cvt_pk_bf16_f32)
  typedef __attribute__((ext_vector_type(2))) __bf16 bf2;
  bf2 p = __builtin_amdgcn_cvt_pk_bf16_f32(lo, hi);
  return *(unsigned*)&p;
#else
  return (unsigned)f2bf(lo) | ((unsigned)f2bf(hi) << 16);
#endif
}

// ---------------------------------------------------------------------------
// prep_all: tiled transpose W2[FFN][EMB] fp32 -> w2t[EMB][FFN] bf16,
//           plus w1t[f][i] bf16 from W1[i][f] (blockIdx.x==0 column).
// ---------------------------------------------------------------------------
__global__ void prep_all(const float* __restrict__ W1,
                         const float* __restrict__ W2,
                         unsigned short* __restrict__ w1t,
                         unsigned short* __restrict__ w2t) {
  __shared__ float t[32][33];
  const int kb = blockIdx.x * 32;   // FFN tile
  const int nb = blockIdx.y * 32;   // EMB tile
  const int c = threadIdx.x & 31, r0 = threadIdx.x >> 5;
#pragma unroll
  for (int p = 0; p < 4; ++p) {
    int r = r0 + p * 8;
    t[r][c] = W2[(size_t)(kb + r) * EMB + nb + c];
  }
  __syncthreads();
#pragma unroll
  for (int p = 0; p < 4; ++p) {
    int r = r0 + p * 8;
    w2t[(size_t)(nb + r) * FFN + kb + c] = f2bf(t[c][r]);
  }
  if (blockIdx.x == 0) {
    const int base = blockIdx.y * 1024 + threadIdx.x * 4;
#pragma unroll
    for (int e = 0; e < 4; ++e) {
      int idx = base + e;
      int f = idx >> 3, i = idx & 7;
      w1t[idx] = f2bf(W1[i * FFN + f]);
    }
  }
}

// ---------------------------------------------------------------------------
// Fused main, R9: ZERO-LDS / ZERO-BARRIER dataflow kernel.
//   Rationale: w2t slice per block-column (512 KiB) is L2-resident and
//   shared by 256 blocks (FETCH 8.9MB across R5/R7 proves ~no HBM re-read).
//   The LDS staging + 64x {vmcnt(0) drain + s_barrier convoy} existed to
//   avoid HBM traffic that doesn't exist. GEMM2 B-frags are 16B/lane
//   contiguous -> load global->VGPR straight from L2.
//   - No __shared__, no s_barrier, no global_load_lds, no manual waitcnt.
//     Waves fully independent; compiler schedules loads freely.
//   - GEMM1(kc+1) (aw/b4 loads + MFMA + relu/pack/permlane, R7-verified
//     routing) sits between the B-frag loads of kc and the GEMM2 MFMAs of
//     kc -> ~300cy of independent work covers the L2 latency.
//   - af current/next are NAMED regs rotated by assignment (no runtime
//     indexing -> no scratch; R8's spill lesson). acc[4] indexed only by
//     static unroll.
//   - launch_bounds(256,3): reg cap ~170, expect ~140-160 actual. Spill
//     tripwire: WRITE_SIZE must stay 65536 KB.
// ---------------------------------------------------------------------------
__global__ __launch_bounds__(256, 3) void ffq_main(
    const float* __restrict__ x,
    const float* __restrict__ theta,
    const unsigned short* __restrict__ w1t,
    const float* __restrict__ b1,
    const unsigned short* __restrict__ w2t,
    const float* __restrict__ b2,
    float* __restrict__ out) {

  const int tid  = threadIdx.x;
  const int wave = tid >> 6;
  const int lane = tid & 63;
  const int nl   = lane & 31;      // n / tok / f-row index within 32
  const int hi   = lane >> 5;      // which 32-lane half
  const int tok0 = blockIdx.x * BM;
  const int n0   = blockIdx.y * BN;

  // ---- bq: GEMM1 B-frag B[k=q][n=tok]; upper-half k-slots are zero ----
  float cth[8];
  {
    const float4* tp = (const float4*)theta;
    float4 t0 = tp[0], t1 = tp[1];
    cth[0] = __cosf(t0.x); cth[1] = __cosf(t0.y);
    cth[2] = __cosf(t0.z); cth[3] = __cosf(t0.w);
    cth[4] = __cosf(t1.x); cth[5] = __cosf(t1.y);
    cth[6] = __cosf(t1.z); cth[7] = __cosf(t1.w);
  }
  short8 bq;
  {
    const float4* xp =
        (const float4*)(x + (size_t)(tok0 + wave * 32 + nl) * NQ);
    float4 x0 = xp[0], x1 = xp[1];
    float q0 = __cosf(x0.x) * cth[0], q1 = __cosf(x0.y) * cth[1];
    float q2 = __cosf(x0.z) * cth[2], q3 = __cosf(x0.w) * cth[3];
    float q4 = __cosf(x1.x) * cth[4], q5 = __cosf(x1.y) * cth[5];
    float q6 = __cosf(x1.z) * cth[6], q7 = __cosf(x1.w) * cth[7];
    uint4 uu;
    uu.x = pk2bf(q0, q1); uu.y = pk2bf(q2, q3);
    uu.z = pk2bf(q4, q5); uu.w = pk2bf(q6, q7);
    if (hi) { uu.x = 0; uu.y = 0; uu.z = 0; uu.w = 0; }
    bq = *(short8*)&uu;
  }

  // ---- GEMM2 B-frag row bases (L2-resident reads; 16B/lane contiguous) ----
  // B[k][n] frag for 32x32x16: lane holds col=nl, k=hi*8+j
  //   -> addr = (n0 + nt*32 + nl)*FFN + kc*32 + ks*16 + hi*8
  const unsigned short* w2p0 = w2t + (size_t)(n0 +  0 + nl) * FFN + hi * 8;
  const unsigned short* w2p1 = w2t + (size_t)(n0 + 32 + nl) * FFN + hi * 8;
  const unsigned short* w2p2 = w2t + (size_t)(n0 + 64 + nl) * FFN + hi * 8;
  const unsigned short* w2p3 = w2t + (size_t)(n0 + 96 + nl) * FFN + hi * 8;

  f32x16 acc[4];
#pragma unroll
  for (int nt = 0; nt < 4; ++nt)
#pragma unroll
    for (int r = 0; r < 16; ++r) acc[nt][r] = 0.f;

  // ---- GEMM1 -> A-frags for GEMM2 (R7's verified permlane routing) ----
  auto gemm1 = [&](short8 aw, const float4* b4, short8& oA, short8& oB) {
    f32x16 c1;
#pragma unroll
    for (int r = 0; r < 16; ++r) c1[r] = b4[r >> 2][r & 3];  // bias as C-in
    c1 = __builtin_amdgcn_mfma_f32_32x32x16_bf16(aw, bq, c1, 0, 0, 0);
    unsigned Q[8];
#pragma unroll
    for (int p = 0; p < 8; ++p) {
      float lo = c1[2 * p]     > 0.f ? c1[2 * p]     : 0.f;
      float hl = c1[2 * p + 1] > 0.f ? c1[2 * p + 1] : 0.f;
      Q[p] = pk2bf(lo, hl);
    }
    u32x2 s0 = __builtin_amdgcn_permlane32_swap(Q[0], Q[2], false, false);
    u32x2 s1 = __builtin_amdgcn_permlane32_swap(Q[1], Q[3], false, false);
    u32x2 s2 = __builtin_amdgcn_permlane32_swap(Q[4], Q[6], false, false);
    u32x2 s3 = __builtin_amdgcn_permlane32_swap(Q[5], Q[7], false, false);
    uint4 uA; uA.x = s0[0]; uA.y = s1[0]; uA.z = s0[1]; uA.w = s1[1];
    uint4 uB; uB.x = s2[0]; uB.y = s3[0]; uB.z = s2[1]; uB.w = s3[1];
    oA = *(short8*)&uA;
    oB = *(short8*)&uB;
  };

  // ---- prologue: GEMM1(0) into current A-frags ----
  short8 afA_c, afB_c, afA_n, afB_n;
  {
    short8 aw0 = *(const short8*)(w1t + (size_t)nl * NQ);
    float4 b40[4];
#pragma unroll
    for (int g = 0; g < 4; ++g)
      b40[g] = *(const float4*)(b1 + 8 * g + 4 * hi);
    gemm1(aw0, b40, afA_c, afB_c);
  }

#pragma unroll 2
  for (int kc = 0; kc < NCHUNK; ++kc) {
    const int nc = (kc + 1 < NCHUNK) ? kc + 1 : NCHUNK - 1;  // clamp: uniform
    const int ko = kc * BK;   // element offset within a w2 row

    // ---- B-frag loads for chunk kc (direct from L2) ----
    short8 bf00 = *(const short8*)(w2p0 + ko);        // ks=0
    short8 bf10 = *(const short8*)(w2p1 + ko);
    short8 bf20 = *(const short8*)(w2p2 + ko);
    short8 bf30 = *(const short8*)(w2p3 + ko);
    short8 bf01 = *(const short8*)(w2p0 + ko + 16);   // ks=1
    short8 bf11 = *(const short8*)(w2p1 + ko + 16);
    short8 bf21 = *(const short8*)(w2p2 + ko + 16);
    short8 bf31 = *(const short8*)(w2p3 + ko + 16);

    // ---- GEMM1(nc): independent of the loads above -> covers L2 latency --
    {
      short8 aw = *(const short8*)(w1t + (size_t)(nc * BK + nl) * NQ);
      float4 b4[4];
#pragma unroll
      for (int g = 0; g < 4; ++g)
        b4[g] = *(const float4*)(b1 + nc * BK + 8 * g + 4 * hi);
      gemm1(aw, b4, afA_n, afB_n);
    }

    // ---- GEMM2(kc): 8 x 32x32x16 ----
    acc[0] = __builtin_amdgcn_mfma_f32_32x32x16_bf16(afA_c, bf00, acc[0], 0, 0, 0);
    acc[1] = __builtin_amdgcn_mfma_f32_32x32x16_bf16(afA_c, bf10, acc[1], 0, 0, 0);
    acc[2] = __builtin_amdgcn_mfma_f32_32x32x16_bf16(afA_c, bf20, acc[2], 0, 0, 0);
    acc[3] = __builtin_amdgcn_mfma_f32_32x32x16_bf16(afA_c, bf30, acc[3], 0, 0, 0);
    acc[0] = __builtin_amdgcn_mfma_f32_32x32x16_bf16(afB_c, bf01, acc[0], 0, 0, 0);
    acc[1] = __builtin_amdgcn_mfma_f32_32x32x16_bf16(afB_c, bf11, acc[1], 0, 0, 0);
    acc[2] = __builtin_amdgcn_mfma_f32_32x32x16_bf16(afB_c, bf21, acc[2], 0, 0, 0);
    acc[3] = __builtin_amdgcn_mfma_f32_32x32x16_bf16(afB_c, bf31, acc[3], 0, 0, 0);

    // rotate A-frags (named regs; unroll-2 eliminates the copies)
    afA_c = afA_n;
    afB_c = afB_n;
  }

  // ---- epilogue: + b2, fp32 store ----
#pragma unroll
  for (int nt = 0; nt < 4; ++nt) {
    const int col = n0 + nt * 32 + nl;
    const float bv = b2[col];
    const int rbase = tok0 + wave * 32 + 4 * hi;
#pragma unroll
    for (int g2 = 0; g2 < 4; ++g2)
#pragma unroll
      for (int rr = 0; rr < 4; ++rr)
        out[(size_t)(rbase + 8 * g2 + rr) * EMB + col] =
            acc[nt][4 * g2 + rr] + bv;
  }
}

extern "C" void kernel_launch(void* const* d_in, const int* in_sizes, int n_in,
                              void* d_out, int out_size, void* d_ws, size_t ws_size,
                              hipStream_t stream) {
  const float* x     = (const float*)d_in[0];
  const float* theta = (const float*)d_in[1];
  const float* W1    = (const float*)d_in[2];
  const float* b1    = (const float*)d_in[3];
  const float* W2    = (const float*)d_in[4];
  const float* b2    = (const float*)d_in[5];
  float* out = (float*)d_out;

  unsigned short* w1t = (unsigned short*)d_ws;       // 16384 bf16
  unsigned short* w2t = w1t + FFN * NQ;              // 1048576 bf16

  prep_all<<<dim3(FFN / 32, EMB / 32), 256, 0, stream>>>(W1, W2, w1t, w2t);

  dim3 grid(T_TOK / BM, EMB / BN);  // (256, 4) = 1024 blocks
  ffq_main<<<grid, 256, 0, stream>>>(x, theta, w1t, b1, w2t, b2, out);
}

// Round 8
// 188.656 us; speedup vs baseline: 1.8283x; 1.8283x over previous
//
#include <hip/hip_runtime.h>

#define T_TOK 32768   // B*S
#define NQ    8
#define FFN   2048
#define EMB   512
#define BM    128
#define BN    128
#define BK    32
#define NCHUNK (FFN / BK)   // 64

typedef __attribute__((ext_vector_type(8)))  short short8;
typedef __attribute__((ext_vector_type(16))) float f32x16;
typedef __attribute__((ext_vector_type(2)))  unsigned int u32x2;

__device__ __forceinline__ unsigned short f2bf(float f) {
  unsigned int u = __float_as_uint(f);
  u += 0x7fffu + ((u >> 16) & 1u);
  return (unsigned short)(u >> 16);
}

__device__ __forceinline__ unsigned pk2bf(float lo, float hi) {
#if __has_builtin(__builtin_amdgcn_cvt_pk_bf16_f32)
  typedef __attribute__((ext_vector_type(2))) __bf16 bf2;
  bf2 p = __builtin_amdgcn_cvt_pk_bf16_f32(lo, hi);
  return *(unsigned*)&p;
#else
  return (unsigned)f2bf(lo) | ((unsigned)f2bf(hi) << 16);
#endif
}

// ---------------------------------------------------------------------------
// prep_all:
//  (1) W2[FFN][EMB] fp32 -> w2f bf16 in MFMA B-FRAGMENT ORDER:
//      region (nt, kc) of 1024 bf16; elem idx i = ks*512 + lane*8 + e
//      holds W2[k][col] with col = nt*32 + (lane&31),
//      k = kc*32 + ks*16 + (lane>>5)*8 + e.
//      -> main kernel reads a frag as ONE coalesced dwordx4 (lane*16B).
//  (2) w1t16[FFN][16]: k<8 = W1[k][f], k==8 = b1[f] (bias folded as an
//      extra input row; bq supplies 1.0 there), k>8 = 0.
// ---------------------------------------------------------------------------
__global__ void prep_all(const float* __restrict__ W1,
                         const float* __restrict__ b1,
                         const float* __restrict__ W2,
                         unsigned short* __restrict__ w1t,
                         unsigned short* __restrict__ w2f) {
  __shared__ float t[32][33];
  const int kb  = blockIdx.x * 32;   // f tile (kc = blockIdx.x)
  const int nb  = blockIdx.y * 32;   // col tile (nt = blockIdx.y)
  const int tid = threadIdx.x;
  const int c = tid & 31, r0 = tid >> 5;
#pragma unroll
  for (int p = 0; p < 4; ++p)
    t[r0 + p * 8][c] = W2[(size_t)(kb + r0 + p * 8) * EMB + nb + c];
  __syncthreads();
  {
    // thread t writes region elems t*4 .. t*4+3 (8B coalesced)
    const int ks = tid >> 7;
    const int hh = (tid >> 6) & 1;
    const int cc = (tid >> 1) & 31;
    const int e0 = (tid & 1) * 4;
    ushort4 v;
    v.x = f2bf(t[ks * 16 + hh * 8 + e0 + 0][cc]);
    v.y = f2bf(t[ks * 16 + hh * 8 + e0 + 1][cc]);
    v.z = f2bf(t[ks * 16 + hh * 8 + e0 + 2][cc]);
    v.w = f2bf(t[ks * 16 + hh * 8 + e0 + 3][cc]);
    *(ushort4*)(w2f + (size_t)(blockIdx.y * NCHUNK + blockIdx.x) * 1024 +
                tid * 4) = v;
  }
  if (blockIdx.x == 0) {
    // w1t16: each thread writes one 16B half-row (8 shorts)
    const int f     = blockIdx.y * 128 + (tid >> 1);
    const int khalf = tid & 1;
    unsigned short v8[8];
#pragma unroll
    for (int j = 0; j < 8; ++j) {
      const int k = khalf * 8 + j;
      float val = (k < 8) ? W1[(size_t)k * FFN + f]
                          : (k == 8 ? b1[f] : 0.f);
      v8[j] = f2bf(val);
    }
    *(uint4*)(w1t + (size_t)f * 16 + khalf * 8) = *(uint4*)v8;
  }
}

// ---------------------------------------------------------------------------
// Fused main, R10: zero-LDS / zero-barrier dataflow with COALESCED frag loads.
//   R9's failure was uncoalesced B-reads (lane-row-strided, 64 lines/load).
//   w2f's fragment order makes each B-frag one lane-linear dwordx4 from
//   L2/L1 (2 MiB total, fully cache-resident; 4 waves/block share lines).
//   - No __shared__, no s_barrier, no waitcnt asm: waves free-run; the
//     ~110us barrier-equilibrium chain loses drain+barrier+ds_read legs.
//   - Bias folded into w1t k=8 row (bq hi-half elem0 = 1.0): kills the
//     16-reg b4 block and 4 loads per chunk (register ceiling: arch+acc
//     must stay <= 128 for 4 blocks/CU; R9's 148 cost a block).
//   - gemm1(nc) between ks0-frag loads and their MFMAs covers L2 latency.
// ---------------------------------------------------------------------------
__global__ __launch_bounds__(256, 4) void ffq_main(
    const float* __restrict__ x,
    const float* __restrict__ theta,
    const unsigned short* __restrict__ w1t,
    const unsigned short* __restrict__ w2f,
    const float* __restrict__ b2,
    float* __restrict__ out) {

  const int tid  = threadIdx.x;
  const int wave = tid >> 6;
  const int lane = tid & 63;
  const int nl   = lane & 31;
  const int hi   = lane >> 5;
  const int tok0 = blockIdx.x * BM;
  const int nt0  = blockIdx.y * 4;   // first of 4 col-tiles (BN=128)

  // ---- bq: B[k=q][tok]; hi half = bias row selector (k=8 -> 1.0) ----
  float cth[8];
  {
    const float4* tp = (const float4*)theta;
    float4 t0 = tp[0], t1 = tp[1];
    cth[0] = __cosf(t0.x); cth[1] = __cosf(t0.y);
    cth[2] = __cosf(t0.z); cth[3] = __cosf(t0.w);
    cth[4] = __cosf(t1.x); cth[5] = __cosf(t1.y);
    cth[6] = __cosf(t1.z); cth[7] = __cosf(t1.w);
  }
  short8 bq;
  {
    const float4* xp =
        (const float4*)(x + (size_t)(tok0 + wave * 32 + nl) * NQ);
    float4 x0 = xp[0], x1 = xp[1];
    float q0 = __cosf(x0.x) * cth[0], q1 = __cosf(x0.y) * cth[1];
    float q2 = __cosf(x0.z) * cth[2], q3 = __cosf(x0.w) * cth[3];
    float q4 = __cosf(x1.x) * cth[4], q5 = __cosf(x1.y) * cth[5];
    float q6 = __cosf(x1.z) * cth[6], q7 = __cosf(x1.w) * cth[7];
    uint4 uu;
    uu.x = pk2bf(q0, q1); uu.y = pk2bf(q2, q3);
    uu.z = pk2bf(q4, q5); uu.w = pk2bf(q6, q7);
    if (hi) { uu.x = 0x00003f80u; uu.y = 0; uu.z = 0; uu.w = 0; }  // k=8: 1.0
    bq = *(short8*)&uu;
  }

  const unsigned short* w2fl = w2f + (size_t)lane * 8;   // lane's 16B slot

  f32x16 acc[4];
#pragma unroll
  for (int nt = 0; nt < 4; ++nt)
#pragma unroll
    for (int r = 0; r < 16; ++r) acc[nt][r] = 0.f;

  // ---- GEMM1 for chunk kcx -> A-frags (R7-verified permlane routing) ----
  auto gemm1 = [&](int kcx, short8& oA, short8& oB) {
    short8 aw = *(const short8*)(w1t + (size_t)(kcx * BK + nl) * 16 + hi * 8);
    f32x16 c1;
#pragma unroll
    for (int r = 0; r < 16; ++r) c1[r] = 0.f;
    c1 = __builtin_amdgcn_mfma_f32_32x32x16_bf16(aw, bq, c1, 0, 0, 0);
    unsigned Q[8];
#pragma unroll
    for (int p = 0; p < 8; ++p) {
      float lo = c1[2 * p]     > 0.f ? c1[2 * p]     : 0.f;
      float hl = c1[2 * p + 1] > 0.f ? c1[2 * p + 1] : 0.f;
      Q[p] = pk2bf(lo, hl);
    }
    u32x2 s0 = __builtin_amdgcn_permlane32_swap(Q[0], Q[2], false, false);
    u32x2 s1 = __builtin_amdgcn_permlane32_swap(Q[1], Q[3], false, false);
    u32x2 s2 = __builtin_amdgcn_permlane32_swap(Q[4], Q[6], false, false);
    u32x2 s3 = __builtin_amdgcn_permlane32_swap(Q[5], Q[7], false, false);
    uint4 uA; uA.x = s0[0]; uA.y = s1[0]; uA.z = s0[1]; uA.w = s1[1];
    uint4 uB; uB.x = s2[0]; uB.y = s3[0]; uB.z = s2[1]; uB.w = s3[1];
    oA = *(short8*)&uA;
    oB = *(short8*)&uB;
  };

  short8 afA_c, afB_c, afA_n, afB_n;
  gemm1(0, afA_c, afB_c);

#pragma unroll 2
  for (int kc = 0; kc < NCHUNK; ++kc) {
    const int nc   = (kc + 1 < NCHUNK) ? kc + 1 : NCHUNK - 1;
    const int base = (nt0 * NCHUNK + kc) * 1024;   // shorts

    // ---- ks=0 frag loads (each: one coalesced dwordx4) ----
    short8 bf0 = *(const short8*)(w2fl + base);
    short8 bf1 = *(const short8*)(w2fl + base + 1 * NCHUNK * 1024);
    short8 bf2 = *(const short8*)(w2fl + base + 2 * NCHUNK * 1024);
    short8 bf3 = *(const short8*)(w2fl + base + 3 * NCHUNK * 1024);

    // ---- GEMM1(nc): independent -> covers the L2 latency above ----
    gemm1(nc, afA_n, afB_n);

    acc[0] = __builtin_amdgcn_mfma_f32_32x32x16_bf16(afA_c, bf0, acc[0], 0, 0, 0);
    acc[1] = __builtin_amdgcn_mfma_f32_32x32x16_bf16(afA_c, bf1, acc[1], 0, 0, 0);
    acc[2] = __builtin_amdgcn_mfma_f32_32x32x16_bf16(afA_c, bf2, acc[2], 0, 0, 0);
    acc[3] = __builtin_amdgcn_mfma_f32_32x32x16_bf16(afA_c, bf3, acc[3], 0, 0, 0);

    // ---- ks=1 frag loads (reuse regs; covered by the 4 MFMAs above) ----
    bf0 = *(const short8*)(w2fl + base + 512);
    bf1 = *(const short8*)(w2fl + base + 1 * NCHUNK * 1024 + 512);
    bf2 = *(const short8*)(w2fl + base + 2 * NCHUNK * 1024 + 512);
    bf3 = *(const short8*)(w2fl + base + 3 * NCHUNK * 1024 + 512);

    acc[0] = __builtin_amdgcn_mfma_f32_32x32x16_bf16(afB_c, bf0, acc[0], 0, 0, 0);
    acc[1] = __builtin_amdgcn_mfma_f32_32x32x16_bf16(afB_c, bf1, acc[1], 0, 0, 0);
    acc[2] = __builtin_amdgcn_mfma_f32_32x32x16_bf16(afB_c, bf2, acc[2], 0, 0, 0);
    acc[3] = __builtin_amdgcn_mfma_f32_32x32x16_bf16(afB_c, bf3, acc[3], 0, 0, 0);

    afA_c = afA_n;
    afB_c = afB_n;
  }

  // ---- epilogue: + b2, fp32 store ----
#pragma unroll
  for (int nt = 0; nt < 4; ++nt) {
    const int col = (nt0 + nt) * 32 + nl;
    const float bv = b2[col];
    const int rbase = tok0 + wave * 32 + 4 * hi;
#pragma unroll
    for (int g2 = 0; g2 < 4; ++g2)
#pragma unroll
      for (int rr = 0; rr < 4; ++rr)
        out[(size_t)(rbase + 8 * g2 + rr) * EMB + col] =
            acc[nt][4 * g2 + rr] + bv;
  }
}

extern "C" void kernel_launch(void* const* d_in, const int* in_sizes, int n_in,
                              void* d_out, int out_size, void* d_ws, size_t ws_size,
                              hipStream_t stream) {
  const float* x     = (const float*)d_in[0];
  const float* theta = (const float*)d_in[1];
  const float* W1    = (const float*)d_in[2];
  const float* b1    = (const float*)d_in[3];
  const float* W2    = (const float*)d_in[4];
  const float* b2    = (const float*)d_in[5];
  float* out = (float*)d_out;

  unsigned short* w1t = (unsigned short*)d_ws;       // FFN*16 = 32768 bf16
  unsigned short* w2f = w1t + FFN * 16;              // 1048576 bf16 (frag order)

  prep_all<<<dim3(FFN / 32, EMB / 32), 256, 0, stream>>>(W1, b1, W2, w1t, w2f);

  dim3 grid(T_TOK / BM, EMB / BN);  // (256, 4) = 1024 blocks = 4/CU resident
  ffq_main<<<grid, 256, 0, stream>>>(x, theta, w1t, w2f, b2, out);
}

// Round 9
// 158.014 us; speedup vs baseline: 2.1828x; 1.1939x over previous
//
#include <hip/hip_runtime.h>

#define T_TOK 32768   // B*S
#define NQ    8
#define FFN   2048
#define EMB   512
#define BM    128
#define BN    256
#define BK    32
#define NCHUNK (FFN / BK)   // 64

typedef __attribute__((ext_vector_type(8)))  short short8;
typedef __attribute__((ext_vector_type(16))) float f32x16;
typedef __attribute__((ext_vector_type(2)))  unsigned int u32x2;

__device__ __forceinline__ unsigned short f2bf(float f) {
  unsigned int u = __float_as_uint(f);
  u += 0x7fffu + ((u >> 16) & 1u);
  return (unsigned short)(u >> 16);
}

__device__ __forceinline__ unsigned pk2bf(float lo, float hi) {
#if __has_builtin(__builtin_amdgcn_cvt_pk_bf16_f32)
  typedef __attribute__((ext_vector_type(2))) __bf16 bf2;
  bf2 p = __builtin_amdgcn_cvt_pk_bf16_f32(lo, hi);
  return *(unsigned*)&p;
#else
  return (unsigned)f2bf(lo) | ((unsigned)f2bf(hi) << 16);
#endif
}

// ---------------------------------------------------------------------------
// prep_all: W2[FFN][EMB] fp32 -> w2t[EMB][FFN] bf16 (tiled transpose), plus
//   w1t16[f][16]: k<8 = W1[k][f], k==8 = b1[f] (bias folded as extra input
//   row; main kernel's bq supplies 1.0 there), k>8 = 0.   (R10-verified)
// ---------------------------------------------------------------------------
__global__ void prep_all(const float* __restrict__ W1,
                         const float* __restrict__ b1,
                         const float* __restrict__ W2,
                         unsigned short* __restrict__ w1t,
                         unsigned short* __restrict__ w2t) {
  __shared__ float t[32][33];
  const int kb = blockIdx.x * 32;   // FFN tile
  const int nb = blockIdx.y * 32;   // EMB tile
  const int tid = threadIdx.x;
  const int c = tid & 31, r0 = tid >> 5;
#pragma unroll
  for (int p = 0; p < 4; ++p) {
    int r = r0 + p * 8;
    t[r][c] = W2[(size_t)(kb + r) * EMB + nb + c];
  }
  __syncthreads();
#pragma unroll
  for (int p = 0; p < 4; ++p) {
    int r = r0 + p * 8;
    w2t[(size_t)(nb + r) * FFN + kb + c] = f2bf(t[c][r]);
  }
  if (blockIdx.x == 0) {
    const int f     = blockIdx.y * 128 + (tid >> 1);
    const int khalf = tid & 1;
    unsigned short v8[8];
#pragma unroll
    for (int j = 0; j < 8; ++j) {
      const int k = khalf * 8 + j;
      float val = (k < 8) ? W1[(size_t)k * FFN + f]
                          : (k == 8 ? b1[f] : 0.f);
      v8[j] = f2bf(val);
    }
    *(uint4*)(w1t + (size_t)f * 16 + khalf * 8) = *(uint4*)v8;
  }
}

// ---------------------------------------------------------------------------
// Fused main, R11: BN=256 — amortize per-chunk fixed costs over 2x MFMA.
//   Synthesis of R0-R10 evidence: wall ~= 3.5x MFMA-floor in every variant;
//   pipes idle, latency-bound. R9/R10: loads must ride the DMA engine
//   (global_load_lds), not the wave's dep chain. Remaining lever: per-wave
//   MFMA per fixed overhead (barrier+gemm1 VALU chain+aw load).
//   - Wave = 32 tok x 256 col: 16 GEMM2-MFMA + 1 gemm1 per chunk (was 8+1).
//   - Grid (256,2) = 512 blocks = 2/CU = 2 waves/SIMD from DIFFERENT blocks
//     (independent barrier domains -> natural desync, no lockstep convoy).
//   - Staging/swizzle: R5/R7-verified scheme extended to 256 rows (4 issues;
//     de-swizzle nt-independent since 32|nt*32 stride keeps (row>>1)&3 = f(nl)).
//   - gemm1: R10-verified bias-folded variant (w1t16 + bq hi-half 1.0).
//   - acc = 8 x f32x16 = 128 AGPR; launch_bounds(256,2) -> 256 regs/wave
//     budget, compiler free to pipeline ds_reads. Spill tripwire: WRITE_SIZE
//     must stay exactly 65536 KB.
// ---------------------------------------------------------------------------
__global__ __launch_bounds__(256, 2) void ffq_main(
    const float* __restrict__ x,
    const float* __restrict__ theta,
    const unsigned short* __restrict__ w1t,
    const unsigned short* __restrict__ w2t,
    const float* __restrict__ b2,
    float* __restrict__ out) {

  __shared__ __align__(16) unsigned short w2_lds[2][BN * BK];   // 32768 B

  const int tid  = threadIdx.x;
  const int wave = tid >> 6;
  const int lane = tid & 63;
  const int nl   = lane & 31;
  const int hi   = lane >> 5;
  const int tok0 = blockIdx.x * BM;
  const int n0   = blockIdx.y * BN;

  // ---- bq: B[k=q][tok]; hi half selects the bias row (k=8 -> 1.0) ----
  float cth[8];
  {
    const float4* tp = (const float4*)theta;
    float4 t0 = tp[0], t1 = tp[1];
    cth[0] = __cosf(t0.x); cth[1] = __cosf(t0.y);
    cth[2] = __cosf(t0.z); cth[3] = __cosf(t0.w);
    cth[4] = __cosf(t1.x); cth[5] = __cosf(t1.y);
    cth[6] = __cosf(t1.z); cth[7] = __cosf(t1.w);
  }
  short8 bq;
  {
    const float4* xp =
        (const float4*)(x + (size_t)(tok0 + wave * 32 + nl) * NQ);
    float4 x0 = xp[0], x1 = xp[1];
    float q0 = __cosf(x0.x) * cth[0], q1 = __cosf(x0.y) * cth[1];
    float q2 = __cosf(x0.z) * cth[2], q3 = __cosf(x0.w) * cth[3];
    float q4 = __cosf(x1.x) * cth[4], q5 = __cosf(x1.y) * cth[5];
    float q6 = __cosf(x1.z) * cth[6], q7 = __cosf(x1.w) * cth[7];
    uint4 uu;
    uu.x = pk2bf(q0, q1); uu.y = pk2bf(q2, q3);
    uu.z = pk2bf(q4, q5); uu.w = pk2bf(q6, q7);
    if (hi) { uu.x = 0x00003f80u; uu.y = 0; uu.z = 0; uu.w = 0; }  // k=8: 1.0
    bq = *(short8*)&uu;
  }

  // ---- w2 staging: linear LDS dest, pre-swizzled global source ----
  // stored 16B-chunk c of row r holds global chunk c ^ ((r>>1)&3);
  // r = issue*64 + (tid>>2), c = tid&3  ->  gc = (tid&3) ^ ((tid>>3)&3).
  const int st_gc = (tid & 3) ^ ((tid >> 3) & 3);
  auto stage_w2 = [&](int kc_, int b_) {
    const int k0_ = kc_ * BK;
#pragma unroll
    for (int issue = 0; issue < 4; ++issue) {
      const int r = issue * 64 + (tid >> 2);
      __builtin_amdgcn_global_load_lds(
          (const __attribute__((address_space(1))) void*)(
              w2t + (size_t)(n0 + r) * FFN + k0_ + st_gc * 8),
          (__attribute__((address_space(3))) void*)(
              &w2_lds[b_][issue * 2048 + tid * 8]),
          16, 0, 0);
    }
  };

  // ---- GEMM2 B-frag read offsets (de-swizzle; nt-independent) ----
  const int swz  = (nl >> 1) & 3;
  const int off0 = nl * 32 + ((0 + hi) ^ swz) * 8;   // ks=0
  const int off1 = nl * 32 + ((2 + hi) ^ swz) * 8;   // ks=1

  f32x16 acc[8];
#pragma unroll
  for (int nt = 0; nt < 8; ++nt)
#pragma unroll
    for (int r = 0; r < 16; ++r) acc[nt][r] = 0.f;

  // ---- GEMM1 -> A-frags (R7/R10-verified permlane routing) ----
  auto gemm1 = [&](short8 aw, short8& oA, short8& oB) {
    f32x16 c1;
#pragma unroll
    for (int r = 0; r < 16; ++r) c1[r] = 0.f;
    c1 = __builtin_amdgcn_mfma_f32_32x32x16_bf16(aw, bq, c1, 0, 0, 0);
    unsigned Q[8];
#pragma unroll
    for (int p = 0; p < 8; ++p) {
      float lo = c1[2 * p]     > 0.f ? c1[2 * p]     : 0.f;
      float hl = c1[2 * p + 1] > 0.f ? c1[2 * p + 1] : 0.f;
      Q[p] = pk2bf(lo, hl);
    }
    u32x2 s0 = __builtin_amdgcn_permlane32_swap(Q[0], Q[2], false, false);
    u32x2 s1 = __builtin_amdgcn_permlane32_swap(Q[1], Q[3], false, false);
    u32x2 s2 = __builtin_amdgcn_permlane32_swap(Q[4], Q[6], false, false);
    u32x2 s3 = __builtin_amdgcn_permlane32_swap(Q[5], Q[7], false, false);
    uint4 uA; uA.x = s0[0]; uA.y = s1[0]; uA.z = s0[1]; uA.w = s1[1];
    uint4 uB; uB.x = s2[0]; uB.y = s3[0]; uB.z = s2[1]; uB.w = s3[1];
    oA = *(short8*)&uA;
    oB = *(short8*)&uB;
  };

  // ---- prologue: stage chunk 0; GEMM1(0) while the stage flies ----
  short8 afA_c, afB_c, afA_n, afB_n;
  {
    stage_w2(0, 0);
    short8 aw0 = *(const short8*)(w1t + (size_t)nl * 16 + hi * 8);
    gemm1(aw0, afA_c, afB_c);
  }

#pragma unroll 2
  for (int kc = 0; kc < NCHUNK; ++kc) {
    const int b  = kc & 1;
    const int nc = (kc + 1 < NCHUNK) ? kc + 1 : NCHUNK - 1;  // clamp: uniform

    // stage(kc) had a full chunk of compute to land -> near-free drain
    asm volatile("s_waitcnt vmcnt(0)" ::: "memory");
    __builtin_amdgcn_s_barrier();   // w2[b] ready; readers of w2[b^1] done
    __builtin_amdgcn_sched_barrier(0);

    // aw for GEMM1(nc): issued early, consumed after 16 MFMAs (covered)
    short8 aw = *(const short8*)(w1t + (size_t)(nc * BK + nl) * 16 + hi * 8);

    stage_w2(nc, b ^ 1);            // prefetch next chunk (stays in flight)

    // ---- GEMM2(kc): 8 col-tiles x 2 ks = 16 x 32x32x16 ----
    const unsigned short* sb = &w2_lds[b][0];
#pragma unroll
    for (int nt = 0; nt < 8; ++nt) {
      short8 bf = *(const short8*)(sb + off0 + nt * 1024);
      acc[nt] = __builtin_amdgcn_mfma_f32_32x32x16_bf16(
          afA_c, bf, acc[nt], 0, 0, 0);
    }
#pragma unroll
    for (int nt = 0; nt < 8; ++nt) {
      short8 bf = *(const short8*)(sb + off1 + nt * 1024);
      acc[nt] = __builtin_amdgcn_mfma_f32_32x32x16_bf16(
          afB_c, bf, acc[nt], 0, 0, 0);
    }

    // ---- GEMM1(nc): VALU chain hides under the MFMA cluster above ----
    gemm1(aw, afA_n, afB_n);
    afA_c = afA_n;
    afB_c = afB_n;
  }

  // drain the clamped last prefetch before LDS goes away
  asm volatile("s_waitcnt vmcnt(0)" ::: "memory");

  // ---- epilogue: + b2, fp32 store ----
#pragma unroll
  for (int nt = 0; nt < 8; ++nt) {
    const int col = n0 + nt * 32 + nl;
    const float bv = b2[col];
    const int rbase = tok0 + wave * 32 + 4 * hi;
#pragma unroll
    for (int g2 = 0; g2 < 4; ++g2)
#pragma unroll
      for (int rr = 0; rr < 4; ++rr)
        out[(size_t)(rbase + 8 * g2 + rr) * EMB + col] =
            acc[nt][4 * g2 + rr] + bv;
  }
}

extern "C" void kernel_launch(void* const* d_in, const int* in_sizes, int n_in,
                              void* d_out, int out_size, void* d_ws, size_t ws_size,
                              hipStream_t stream) {
  const float* x     = (const float*)d_in[0];
  const float* theta = (const float*)d_in[1];
  const float* W1    = (const float*)d_in[2];
  const float* b1    = (const float*)d_in[3];
  const float* W2    = (const float*)d_in[4];
  const float* b2    = (const float*)d_in[5];
  float* out = (float*)d_out;

  unsigned short* w1t = (unsigned short*)d_ws;       // FFN*16 = 32768 bf16
  unsigned short* w2t = w1t + FFN * 16;              // 1048576 bf16 [EMB][FFN]

  prep_all<<<dim3(FFN / 32, EMB / 32), 256, 0, stream>>>(W1, b1, W2, w1t, w2t);

  dim3 grid(T_TOK / BM, EMB / BN);  // (256, 2) = 512 blocks = 2/CU
  ffq_main<<<grid, 256, 0, stream>>>(x, theta, w1t, w2t, b2, out);
}